// Round 6
// baseline (3125.363 us; speedup 1.0000x reference)
//
#include <hip/hip_runtime.h>
#include <math.h>
#include <stdint.h>

#define AG __HIP_MEMORY_SCOPE_AGENT
typedef unsigned long long ull;

// ---- cross-XCD-coherent data ops (per-address at MALL, no cache maintenance)
__device__ __forceinline__ float ld4(const float* p) {
  return __hip_atomic_load(p, __ATOMIC_RELAXED, AG);
}
__device__ __forceinline__ void st4(float* p, float v) {
  __hip_atomic_store(p, v, __ATOMIC_RELAXED, AG);
}
__device__ __forceinline__ ull ld8(const float* p) {
  return __hip_atomic_load((const ull*)p, __ATOMIC_RELAXED, AG);
}
__device__ __forceinline__ void fence_vm() {
  asm volatile("s_waitcnt vmcnt(0)" ::: "memory");
}
__device__ __forceinline__ void waitge(unsigned* c, unsigned tgt) {
  if (threadIdx.x == 0) {
    while ((int)(__hip_atomic_load(c, __ATOMIC_RELAXED, AG) - tgt) < 0)
      __builtin_amdgcn_s_sleep(1);
  }
  __syncthreads();
}
// poll own replica line (<=8 pollers per line)
__device__ __forceinline__ void wait_epoch(unsigned* line, unsigned epoch) {
  if (threadIdx.x == 0) {
    while ((int)(__hip_atomic_load(line, __ATOMIC_RELAXED, AG) - epoch) < 0)
      __builtin_amdgcn_s_sleep(1);
  }
  __syncthreads();
}
__device__ __forceinline__ void wr2(float* d, ull v) {
  d[0] = __uint_as_float((unsigned)v);
  d[1] = __uint_as_float((unsigned)(v >> 32));
}
__device__ __forceinline__ float act_apply(int act, float v) {
  if (act == 0) {  // jax.nn.gelu (tanh approx)
    float v3 = v * v * v;
    return 0.5f * v * (1.0f + tanhf(0.7978845608028654f * (v + 0.044715f * v3)));
  }
  if (act == 1) return tanhf(v);
  return v;
}

// stage signal with optional 64-line broadcast
__device__ __forceinline__ void stage_signal(unsigned* stageCnt, unsigned bcT,
                                             unsigned* flag, unsigned epoch,
                                             unsigned* sflag) {
  const int tid = threadIdx.x;
  if (tid == 0) {
    unsigned old = __hip_atomic_fetch_add(stageCnt, 1u, __ATOMIC_RELAXED, AG);
    *sflag = (bcT && old == bcT - 1) ? 1u : 0u;
  }
  __syncthreads();
  if (*sflag) {
    if (tid < 64) __hip_atomic_store(flag + tid * 16, epoch, __ATOMIC_RELAXED, AG);
  }
  __syncthreads();
}

// ---------------- P4Q: rows=4 encoder stage, fat float4 weight loads ----
// Cell (N=512 out cols) computed by 8 WGs: ct in {0,1} (256-col half),
// kc in {0..3} (K quarter). Within WG: wave q takes KQ k's; lane j takes
// cols c0+4j..4j+3 (float4 W loads -> 1KB/wave-instr). 4-way LDS reduce,
// then cross-WG partial + last-arriver (cumulative kcTgt) reduce.
template <int KQ, class ZL8, class ST>
__device__ void p4q(const float* __restrict__ W, const float* __restrict__ bias,
                    int c0, int kc, int act, unsigned kcTgt,
                    unsigned* kcCnt, float* part, unsigned* stageCnt,
                    float* lds, unsigned* sflag, ZL8&& zl8, ST&& store) {
  const int tid = threadIdx.x;
  const int j = tid & 63, q = tid >> 6;
  constexpr int KC = 4 * KQ;   // per-WG K span
  const int kWG = kc * KC;
  float* z = lds;              // [4][KC]
  float* red = lds + 4 * KC;   // [4][1024]
  __syncthreads();  // protect LDS reuse across stages
  for (int i = tid; i < 2 * KC; i += 256) {  // 4 rows x KC/2 pairs
    int b = i / (KC >> 1), kp = i - b * (KC >> 1);
    wr2(&z[b * KC + 2 * kp], zl8(b, (kWG >> 1) + kp));
  }
  __syncthreads();
  float acc[4][4];
#pragma unroll
  for (int r = 0; r < 4; ++r)
#pragma unroll
    for (int c = 0; c < 4; ++c) acc[r][c] = 0.f;
  const float* wp = W + (size_t)(kWG + q * KQ) * 512 + c0 + 4 * j;
  const float* zq = z + q * KQ;
#pragma unroll 16
  for (int kk = 0; kk < KQ; ++kk) {
    float4 w4 = *(const float4*)(wp + (size_t)kk * 512);
    float z0 = zq[kk], z1 = zq[KC + kk], z2 = zq[2 * KC + kk], z3 = zq[3 * KC + kk];
    acc[0][0] = fmaf(z0, w4.x, acc[0][0]); acc[0][1] = fmaf(z0, w4.y, acc[0][1]);
    acc[0][2] = fmaf(z0, w4.z, acc[0][2]); acc[0][3] = fmaf(z0, w4.w, acc[0][3]);
    acc[1][0] = fmaf(z1, w4.x, acc[1][0]); acc[1][1] = fmaf(z1, w4.y, acc[1][1]);
    acc[1][2] = fmaf(z1, w4.z, acc[1][2]); acc[1][3] = fmaf(z1, w4.w, acc[1][3]);
    acc[2][0] = fmaf(z2, w4.x, acc[2][0]); acc[2][1] = fmaf(z2, w4.y, acc[2][1]);
    acc[2][2] = fmaf(z2, w4.z, acc[2][2]); acc[2][3] = fmaf(z2, w4.w, acc[2][3]);
    acc[3][0] = fmaf(z3, w4.x, acc[3][0]); acc[3][1] = fmaf(z3, w4.y, acc[3][1]);
    acc[3][2] = fmaf(z3, w4.z, acc[3][2]); acc[3][3] = fmaf(z3, w4.w, acc[3][3]);
  }
  // intra-WG reduce across the 4 waves via LDS
  float* myred = red + q * 1024 + j * 16;
#pragma unroll
  for (int b = 0; b < 4; ++b) {
    float4 v4; v4.x = acc[b][0]; v4.y = acc[b][1]; v4.z = acc[b][2]; v4.w = acc[b][3];
    *(float4*)(myred + b * 4) = v4;
  }
  __syncthreads();
  float4 r0 = *(const float4*)(red + 4 * tid);
  float4 r1 = *(const float4*)(red + 1024 + 4 * tid);
  float4 r2 = *(const float4*)(red + 2048 + 4 * tid);
  float4 r3 = *(const float4*)(red + 3072 + 4 * tid);
  float s0 = r0.x + r1.x + r2.x + r3.x;
  float s1 = r0.y + r1.y + r2.y + r3.y;
  float s2 = r0.z + r1.z + r2.z + r3.z;
  float s3 = r0.w + r1.w + r2.w + r3.w;
  st4(&part[kc * 1024 + 4 * tid + 0], s0);
  st4(&part[kc * 1024 + 4 * tid + 1], s1);
  st4(&part[kc * 1024 + 4 * tid + 2], s2);
  st4(&part[kc * 1024 + 4 * tid + 3], s3);
  fence_vm();
  __syncthreads();
  if (tid == 0) {
    unsigned old = __hip_atomic_fetch_add(kcCnt, 1u, __ATOMIC_RELAXED, AG);
    *sflag = (old == kcTgt - 1) ? 1u : 0u;
  }
  __syncthreads();
  if (*sflag) {
    const int b = tid & 3, j2 = tid >> 2;
    const int colb = c0 + 4 * j2;
#pragma unroll
    for (int cc = 0; cc < 4; ++cc) {
      int o = 4 * tid + cc;
      float v = ld4(&part[o]) + ld4(&part[1024 + o]) +
                ld4(&part[2048 + o]) + ld4(&part[3072 + o]);
      v += bias[colb + cc];
      v = act_apply(act, v);
      store(b, colb + cc, v);
    }
    fence_vm();
    __syncthreads();
    if (tid == 0) __hip_atomic_fetch_add(stageCnt, 1u, __ATOMIC_RELAXED, AG);
  }
  __syncthreads();
}

// ---------------- P4: rows=4 matmul stage (decoder, unchanged) ----------
template <int KC, class ZL8, class ST>
__device__ void p4(const float* __restrict__ W, int ldw, const float* __restrict__ bias,
                   int c0, int k0, int chunk, int act, int kc, unsigned kcTgt,
                   unsigned* kcCnt, float* part,
                   unsigned* stageCnt, unsigned bcT, unsigned* flag, unsigned epoch,
                   float* lds, unsigned* sflag, ZL8&& zl8, ST&& store) {
  const int tid = threadIdx.x;
  __syncthreads();  // protect LDS reuse across stages
  const int cp = chunk >> 1;  // pairs per row
  for (int i = tid; i < 4 * cp; i += 256) {
    int b = i / cp, kp = i - b * cp;
    ull v = zl8(b, (k0 >> 1) + kp);
    wr2(&lds[b * chunk + 2 * kp], v);
  }
  __syncthreads();
  const int j = tid & 63, kq = tid >> 6;
  const int sub = chunk >> 2;
  float a0 = 0.f, a1 = 0.f, a2 = 0.f, a3 = 0.f;
  const float* wp = W + (size_t)(k0 + kq * sub) * ldw + (c0 + j);
  const float* z0 = lds + kq * sub;
  const float* z1 = z0 + chunk;
  const float* z2 = z1 + chunk;
  const float* z3 = z2 + chunk;
#pragma unroll 16
  for (int kk = 0; kk < sub; ++kk) {
    float wv = wp[(size_t)kk * ldw];
    a0 = fmaf(z0[kk], wv, a0);
    a1 = fmaf(z1[kk], wv, a1);
    a2 = fmaf(z2[kk], wv, a2);
    a3 = fmaf(z3[kk], wv, a3);
  }
  __syncthreads();
  float* red = lds;  // [4q][64j][4b]
  red[tid * 4 + 0] = a0; red[tid * 4 + 1] = a1;
  red[tid * 4 + 2] = a2; red[tid * 4 + 3] = a3;
  __syncthreads();
  const int jj = tid & 63, bb = tid >> 6;
  float v = red[jj * 4 + bb] + red[256 + jj * 4 + bb] +
            red[512 + jj * 4 + bb] + red[768 + jj * 4 + bb];
  if constexpr (KC == 1) {
    v += bias[c0 + jj];
    v = act_apply(act, v);
    store(bb, c0 + jj, v);
    fence_vm();
    __syncthreads();
    stage_signal(stageCnt, bcT, flag, epoch, sflag);
  } else {
    st4(&part[kc * 256 + jj * 4 + bb], v);
    fence_vm();
    __syncthreads();
    if (tid == 0) {
      unsigned old = __hip_atomic_fetch_add(kcCnt, 1u, __ATOMIC_RELAXED, AG);
      *sflag = (old == kcTgt - 1) ? 1u : 0u;
    }
    __syncthreads();
    if (*sflag) {
      float s = 0.f;
#pragma unroll
      for (int q = 0; q < KC; ++q) s += ld4(&part[q * 256 + jj * 4 + bb]);
      s += bias[c0 + jj];
      s = act_apply(act, s);
      store(bb, c0 + jj, s);
      fence_vm();
      __syncthreads();
      stage_signal(stageCnt, bcT, flag, epoch, sflag);
    }
  }
  __syncthreads();
}

// ---------------- P64: rows=64 tiled GEMM stage (FF, unchanged) ---------
template <int KC, class ZL8, class ST>
__device__ void p64(const float* __restrict__ W, int ldw, const float* __restrict__ bias,
                    int c0, int k0, int k1, int act, int kc, unsigned kcTgt,
                    unsigned* kcCnt, float* part,
                    unsigned* stageCnt, unsigned bcT, unsigned* flag, unsigned epoch,
                    float* lds, unsigned* sflag, ZL8&& zl8, ST&& store) {
  const int tid = threadIdx.x;
  const int tj = tid & 15, tr = tid >> 4;
  float acc[4][4];
#pragma unroll
  for (int r = 0; r < 4; ++r)
#pragma unroll
    for (int c = 0; c < 4; ++c) acc[r][c] = 0.f;
  float* Wl = lds;            // [64][68]
  float* Zl = lds + 64 * 68;  // [64][65]
  const int wk = tid >> 2, wc = (tid & 3) * 16;
  const int r1 = tid >> 3, c8 = tid & 7;
  for (int kb = k0; kb < k1; kb += 64) {
    __syncthreads();
    {  // W: normal (cached) loads, 64B/thread
      const float* src = W + (size_t)(kb + wk) * ldw + c0 + wc;
      float4 w0 = *(const float4*)(src);
      float4 w1 = *(const float4*)(src + 4);
      float4 w2 = *(const float4*)(src + 8);
      float4 w3 = *(const float4*)(src + 12);
      *(float4*)&Wl[wk * 68 + wc + 0]  = w0;
      *(float4*)&Wl[wk * 68 + wc + 4]  = w1;
      *(float4*)&Wl[wk * 68 + wc + 8]  = w2;
      *(float4*)&Wl[wk * 68 + wc + 12] = w3;
    }
    {  // Z: coherent pair loads; 8 lanes cover one 64B line per instr
      ull v[8];
#pragma unroll
      for (int qq = 0; qq < 8; ++qq) {
        int row = (qq < 4) ? r1 : 32 + r1;
        int kp = c8 + 8 * (qq & 3);
        v[qq] = zl8(row, (kb >> 1) + kp);
      }
#pragma unroll
      for (int qq = 0; qq < 8; ++qq) {
        int row = (qq < 4) ? r1 : 32 + r1;
        int kp = c8 + 8 * (qq & 3);
        wr2(&Zl[row * 65 + 2 * kp], v[qq]);
      }
    }
    __syncthreads();
#pragma unroll 4
    for (int kk = 0; kk < 64; ++kk) {
      float4 w4 = *(float4*)&Wl[kk * 68 + tj * 4];
      float zr0 = Zl[(tr * 4 + 0) * 65 + kk];
      float zr1 = Zl[(tr * 4 + 1) * 65 + kk];
      float zr2 = Zl[(tr * 4 + 2) * 65 + kk];
      float zr3 = Zl[(tr * 4 + 3) * 65 + kk];
      acc[0][0] = fmaf(zr0, w4.x, acc[0][0]); acc[0][1] = fmaf(zr0, w4.y, acc[0][1]);
      acc[0][2] = fmaf(zr0, w4.z, acc[0][2]); acc[0][3] = fmaf(zr0, w4.w, acc[0][3]);
      acc[1][0] = fmaf(zr1, w4.x, acc[1][0]); acc[1][1] = fmaf(zr1, w4.y, acc[1][1]);
      acc[1][2] = fmaf(zr1, w4.z, acc[1][2]); acc[1][3] = fmaf(zr1, w4.w, acc[1][3]);
      acc[2][0] = fmaf(zr2, w4.x, acc[2][0]); acc[2][1] = fmaf(zr2, w4.y, acc[2][1]);
      acc[2][2] = fmaf(zr2, w4.z, acc[2][2]); acc[2][3] = fmaf(zr2, w4.w, acc[2][3]);
      acc[3][0] = fmaf(zr3, w4.x, acc[3][0]); acc[3][1] = fmaf(zr3, w4.y, acc[3][1]);
      acc[3][2] = fmaf(zr3, w4.z, acc[3][2]); acc[3][3] = fmaf(zr3, w4.w, acc[3][3]);
    }
  }
  __syncthreads();
  if constexpr (KC == 1) {
#pragma unroll
    for (int r = 0; r < 4; ++r)
#pragma unroll
      for (int c = 0; c < 4; ++c) {
        int col = c0 + tj * 4 + c;
        float v = acc[r][c] + bias[col];
        v = act_apply(act, v);
        store(tr * 4 + r, col, v);
      }
    fence_vm();
    __syncthreads();
    stage_signal(stageCnt, bcT, flag, epoch, sflag);
  } else {
    float* pp = part + kc * 4096;
#pragma unroll
    for (int r = 0; r < 4; ++r)
#pragma unroll
      for (int c = 0; c < 4; ++c)
        st4(&pp[(tr * 4 + r) * 64 + tj * 4 + c], acc[r][c]);
    fence_vm();
    __syncthreads();
    if (tid == 0) {
      unsigned old = __hip_atomic_fetch_add(kcCnt, 1u, __ATOMIC_RELAXED, AG);
      *sflag = (old == kcTgt - 1) ? 1u : 0u;
    }
    __syncthreads();
    if (*sflag) {
      for (int r = 0; r < 4; ++r)
        for (int c = 0; c < 4; ++c) {
          int idx = (tr * 4 + r) * 64 + tj * 4 + c;
          float s = 0.f;
#pragma unroll
          for (int q = 0; q < KC; ++q) s += ld4(&part[q * 4096 + idx]);
          int col = c0 + tj * 4 + c;
          s += bias[col];
          s = act_apply(act, s);
          store(tr * 4 + r, col, s);
        }
      fence_vm();
      __syncthreads();
      stage_signal(stageCnt, bcT, flag, epoch, sflag);
    }
  }
  __syncthreads();
}

struct P {
  const float *x;
  const float *e0W0, *e0b0, *e0W1, *e0b1, *e0W2, *e0b2;
  const float *erW0, *erb0, *erW1, *erb1, *erW2, *erb2;
  const float *ffW0, *ffb0, *ffW1, *ffb1;
  const float *dW0, *db0, *dWh, *dbh, *dWo, *dbo;
  float *S, *h1, *h2, *g, *eo, *hd0, *hd1, *dob, *pENC, *pF2, *pD;
  unsigned* cnt;
  float* out;
};

// S layout: S[r][t][e][b][512]
#define S_IDX(r, t, e, b) ((size_t)((((r)*16 + (t)) * 16 + (e)) * 4 + (b)) * 512)

// counter map: each logical counter = one 64B line; cptr(i) = cnt + i*16
#define C_A 0        // aT[e*4+lvl]          (64)
#define C_B 64       // bT                   (64)
#define C_C 128      // cT                   (64)
#define C_KA 192     // kA[e*8+lvl*2+ct]     (128)
#define C_KB 320     // kB                   (128)
#define C_KC 448     // kC                   (128)
#define C_FFG 576    // ffg[e]               (16)
#define C_KF2 592    // kcF2[e*8+ct]         (128)
#define C_FFO 720    // ffo                  (1)
#define C_DC 728     // dcnt[6]              (6)
#define C_KD 736     // kcD[32]              (32)
#define C_KDO 768    // kcDo[16]             (16)
#define C_FFLAG 784  // flagFF               (64 lines)
#define C_OFLAG 848  // flagOut              (64 lines)
#define C_DFLAG 912  // flagD[5]             (5*64 lines, end 1232)

__global__ __launch_bounds__(256, 2) void hrnn(P p) {
  __shared__ __align__(16) float lds[64 * 68 + 64 * 65];
  __shared__ unsigned sflag;
  const int w = blockIdx.x;
  auto cptr = [&](int i) { return p.cnt + (size_t)i * 16; };
  unsigned* myline_ff = cptr(C_FFLAG + (w & 63));
  unsigned* myline_out = cptr(C_OFLAG + (w & 63));

  // ======== ENCODERS: wavefront over (lvl,t); 8 WGs per (e,lvl) cell =====
  // role: lvl(4) x ct(2 col-halves) x kcq(4 K-quarters). All WGs of encoder
  // e land on XCD e%8 (w = e mod 16).
  {
    const int e = w & 15, role = w >> 4;
    const int lvl = role & 3, ct = (role >> 2) & 1, kcq = role >> 3;
    const int c0 = ct * 256;
    const float *W0, *B0, *W1, *B1, *W2, *B2;
    if (lvl == 0) {
      W0 = p.e0W0 + (size_t)e * 544 * 512; B0 = p.e0b0 + e * 512;
      W1 = p.e0W1 + (size_t)e * 262144;    B1 = p.e0b1 + e * 512;
      W2 = p.e0W2 + (size_t)e * 262144;    B2 = p.e0b2 + e * 512;
    } else {
      int ri = (lvl - 1) * 16 + e;
      W0 = p.erW0 + (size_t)ri * 524288; B0 = p.erb0 + (size_t)ri * 512;
      W1 = p.erW1 + (size_t)ri * 262144; B1 = p.erb1 + (size_t)ri * 512;
      W2 = p.erW2 + (size_t)ri * 262144; B2 = p.erb2 + (size_t)ri * 512;
    }
    unsigned* aT = cptr(C_A + e * 4 + lvl);
    unsigned* bT = cptr(C_B + e * 4 + lvl);
    unsigned* cT = cptr(C_C + e * 4 + lvl);
    const int gi = e * 8 + lvl * 2 + ct;
    unsigned* kA = cptr(C_KA + gi);
    unsigned* kB = cptr(C_KB + gi);
    unsigned* kC = cptr(C_KC + gi);
    float* pA = p.pENC + (size_t)gi * 4096;
    float* pB = pA + (size_t)128 * 4096;
    float* pC = pB + (size_t)128 * 4096;
    float* h1 = p.h1 + (size_t)(e * 4 + lvl) * 2048;
    float* h2 = p.h2 + (size_t)(e * 4 + lvl) * 2048;
    for (int t = 0; t < 16; ++t) {
      if (t) waitge(cT, 2u * t);                                   // own S[t-1]
      if (lvl) waitge(cptr(C_C + e * 4 + lvl - 1), 2u * (t + 1));  // S[lvl-1][t]
      {  // stage A
        const float* x = p.x; const float* S = p.S;
        const int tt = t, ee = e, rr = lvl;
        auto st = [=](int b, int col, float v) { st4(h1 + b * 512 + col, v); };
        if (rr == 0) {
          auto zl = [=](int b, int kp) -> ull {
            if (kp < 16) return *(const ull*)(x + ((b * 16 + tt) * 32 + 2 * kp));
            return tt ? ld8(S + S_IDX(0, tt - 1, ee, b) + 2 * kp - 32) : 0ull;
          };
          p4q<34>(W0, B0, c0, kcq, 0, 4u * (t + 1), kA, pA, aT, lds, &sflag, zl, st);
        } else {
          auto zl = [=](int b, int kp) -> ull {
            if (kp < 256) return ld8(S + S_IDX(rr - 1, tt, ee, b) + 2 * kp);
            return tt ? ld8(S + S_IDX(rr, tt - 1, ee, b) + 2 * kp - 512) : 0ull;
          };
          p4q<64>(W0, B0, c0, kcq, 0, 4u * (t + 1), kA, pA, aT, lds, &sflag, zl, st);
        }
      }
      waitge(aT, 2u * (t + 1));
      {  // stage B
        auto zl = [=](int b, int kp) -> ull { return ld8(h1 + b * 512 + 2 * kp); };
        auto st = [=](int b, int col, float v) { st4(h2 + b * 512 + col, v); };
        p4q<32>(W1, B1, c0, kcq, 0, 4u * (t + 1), kB, pB, bT, lds, &sflag, zl, st);
      }
      waitge(bT, 2u * (t + 1));
      {  // stage C
        float* S = p.S; const int tt = t, ee = e, rr = lvl;
        auto zl = [=](int b, int kp) -> ull { return ld8(h2 + b * 512 + 2 * kp); };
        auto st = [=](int b, int col, float v) { st4(S + S_IDX(rr, tt, ee, b) + col, v); };
        p4q<32>(W2, B2, c0, kcq, 1, 4u * (t + 1), kC, pC, cT, lds, &sflag, zl, st);
      }
    }
  }

  // ======== FF1: rows=64 (t,b), K=2048, 32 col-tiles per e ================
  const int e = w & 15;
  for (int r = 0; r < 4; ++r) waitge(cptr(C_C + e * 4 + r), 32u);
  {
    const float* S = p.S; const int ee = e;
    auto zl = [=](int row, int kp) -> ull {
      int k = 2 * kp, tt = row >> 2, b = row & 3, seg = k >> 9;
      return ld8(S + S_IDX(seg, tt, ee, b) + (k & 511));
    };
    float* g = p.g + (size_t)e * 131072;
    auto st = [=](int row, int col, float v) { st4(g + (size_t)row * 2048 + col, v); };
    int slot = w >> 4;
    p64<1>(p.ffW0 + (size_t)e * 4194304, 2048, p.ffb0 + e * 2048, slot * 64, 0, 2048,
           0, 0, 0, nullptr, nullptr, cptr(C_FFG + e), 0, nullptr, 0,
           lds, &sflag, zl, st);
  }
  waitge(cptr(C_FFG + e), 32u);
  // ======== FF2: K=2048 split 4; completion broadcast to flagFF ===========
  {
    int ct2 = w >> 6, kc2 = (w >> 4) & 3;
    const float* g = p.g + (size_t)e * 131072;
    auto zl = [=](int row, int kp) -> ull { return ld8(g + (size_t)row * 2048 + 2 * kp); };
    float* eo = p.eo; const int ee = e;
    auto st = [=](int row, int col, float v) {
      int tt = row >> 2, b = row & 3;
      st4(eo + (size_t)((tt * 16 + ee) * 4 + b) * 512 + col, v);
    };
    p64<4>(p.ffW1 + (size_t)e * 1048576, 512, p.ffb1 + e * 512, ct2 * 64,
           kc2 * 512, (kc2 + 1) * 512, 2, kc2, 4u,
           cptr(C_KF2 + e * 8 + ct2), p.pF2 + (size_t)(e * 8 + ct2) * 16384,
           cptr(C_FFO), 128u, cptr(C_FFLAG), 1u, lds, &sflag, zl, st);
  }

  // ======== DECODER: sequential over t, broadcast-flag sync ===============
  wait_epoch(myline_ff, 1u);
  {
    const int tile = w >> 4, kD = w & 15;   // layers 0..4: 32 tiles x 16 kc
    const int tileO = w >> 5, kO = w & 31;  // out: 16 tiles x 32 kc
    for (int t = 0; t < 16; ++t) {
      if (t) wait_epoch(myline_out, (unsigned)t);
      {  // layer 0: z = [encout(8192), dec_s(1024)], K=9216 split 16
        const float* eo = p.eo; const float* dob = p.dob; const int tt = t;
        auto zl = [=](int b, int kp) -> ull {
          int k = 2 * kp;
          if (k < 8192) {
            int e2 = k >> 9;
            return ld8(eo + (size_t)((tt * 16 + e2) * 4 + b) * 512 + (k & 511));
          }
          return tt ? ld8(dob + b * 1024 + (k - 8192)) : 0ull;
        };
        float* hd = p.hd0;
        auto st = [=](int b, int col, float v) { st4(hd + b * 2048 + col, v); };
        p4<16>(p.dW0, 2048, p.db0, tile * 64, kD * 576, 576, 0, kD, 80u * t + 16u,
               cptr(C_KD + tile), p.pD + (size_t)tile * 4096,
               cptr(C_DC + 0), 32u * (t + 1), cptr(C_DFLAG + 0 * 64), (unsigned)(t + 1),
               lds, &sflag, zl, st);
      }
      for (int l = 1; l <= 4; ++l) {
        wait_epoch(cptr(C_DFLAG + (l - 1) * 64 + (w & 63)), (unsigned)(t + 1));
        const float* hin = (l & 1) ? p.hd0 : p.hd1;
        float* hout = (l & 1) ? p.hd1 : p.hd0;
        auto zl = [=](int b, int kp) -> ull { return ld8(hin + b * 2048 + 2 * kp); };
        auto st = [=](int b, int col, float v) { st4(hout + b * 2048 + col, v); };
        p4<16>(p.dWh + (size_t)(l - 1) * 4194304, 2048, p.dbh + (size_t)(l - 1) * 2048,
               tile * 64, kD * 128, 128, 0, kD, 80u * t + 16u * (l + 1),
               cptr(C_KD + tile), p.pD + (size_t)tile * 4096,
               cptr(C_DC + l), 32u * (t + 1), cptr(C_DFLAG + l * 64), (unsigned)(t + 1),
               lds, &sflag, zl, st);
      }
      wait_epoch(cptr(C_DFLAG + 4 * 64 + (w & 63)), (unsigned)(t + 1));
      {  // out layer: tanh -> d_out and dec state
        const float* hin = p.hd0; float* dob = p.dob; float* outp = p.out; const int tt = t;
        auto zl = [=](int b, int kp) -> ull { return ld8(hin + b * 2048 + 2 * kp); };
        auto st = [=](int b, int col, float v) {
          outp[(size_t)(b * 16 + tt) * 1024 + col] = v;  // host-visible
          st4(dob + b * 1024 + col, v);
        };
        p4<32>(p.dWo, 1024, p.dbo, tileO * 64, kO * 64, 64, 1, kO, 32u * (t + 1),
               cptr(C_KDO + tileO), p.pD + (size_t)tileO * 8192,
               cptr(C_DC + 5), 16u * (t + 1), cptr(C_OFLAG), (unsigned)(t + 1),
               lds, &sflag, zl, st);
      }
    }
  }
}

extern "C" void kernel_launch(void* const* d_in, const int* in_sizes, int n_in,
                              void* d_out, int out_size, void* d_ws, size_t ws_size,
                              hipStream_t stream) {
  hipMemsetAsync(d_ws, 0, 131072, stream);  // zero padded counters + flags

  P p;
  p.x    = (const float*)d_in[0];
  p.e0W0 = (const float*)d_in[1];  p.e0b0 = (const float*)d_in[2];
  p.e0W1 = (const float*)d_in[3];  p.e0b1 = (const float*)d_in[4];
  p.e0W2 = (const float*)d_in[5];  p.e0b2 = (const float*)d_in[6];
  p.erW0 = (const float*)d_in[7];  p.erb0 = (const float*)d_in[8];
  p.erW1 = (const float*)d_in[9];  p.erb1 = (const float*)d_in[10];
  p.erW2 = (const float*)d_in[11]; p.erb2 = (const float*)d_in[12];
  p.ffW0 = (const float*)d_in[13]; p.ffb0 = (const float*)d_in[14];
  p.ffW1 = (const float*)d_in[15]; p.ffb1 = (const float*)d_in[16];
  p.dW0  = (const float*)d_in[17]; p.db0  = (const float*)d_in[18];
  p.dWh  = (const float*)d_in[19]; p.dbh  = (const float*)d_in[20];
  p.dWo  = (const float*)d_in[21]; p.dbo  = (const float*)d_in[22];

  float* base = (float*)((char*)d_ws + 131072);
  p.S    = base; base += 2097152;  // 4*16*16*4*512
  p.h1   = base; base += 131072;   // 16*4 cells * 4*512
  p.h2   = base; base += 131072;
  p.g    = base; base += 2097152;  // 16*64*2048
  p.eo   = base; base += 524288;   // 16*16*4*512
  p.hd0  = base; base += 8192;
  p.hd1  = base; base += 8192;
  p.dob  = base; base += 4096;
  p.pENC = base; base += 1572864;  // 3 stages * 128 groups * 4096
  p.pF2  = base; base += 2097152;  // 16*8*4*4096
  p.pD   = base; base += 131072;   // 32*16*256 == 16*32*256

  p.cnt = (unsigned*)d_ws;
  p.out = (float*)d_out;

  hipLaunchKernelGGL(hrnn, dim3(512), dim3(256), 0, stream, p);
}

// Round 7
// 2124.615 us; speedup vs baseline: 1.4710x; 1.4710x over previous
//
#include <hip/hip_runtime.h>
#include <math.h>
#include <stdint.h>

#define AG __HIP_MEMORY_SCOPE_AGENT
typedef unsigned long long ull;

// ---- cross-XCD-coherent data ops (per-address at MALL, no cache maintenance)
__device__ __forceinline__ float ld4(const float* p) {
  return __hip_atomic_load(p, __ATOMIC_RELAXED, AG);
}
__device__ __forceinline__ void st4(float* p, float v) {
  __hip_atomic_store(p, v, __ATOMIC_RELAXED, AG);
}
__device__ __forceinline__ ull ld8(const float* p) {
  return __hip_atomic_load((const ull*)p, __ATOMIC_RELAXED, AG);
}
__device__ __forceinline__ void fence_vm() {
  asm volatile("s_waitcnt vmcnt(0)" ::: "memory");
}
__device__ __forceinline__ void waitge(unsigned* c, unsigned tgt) {
  if (threadIdx.x == 0) {
    while ((int)(__hip_atomic_load(c, __ATOMIC_RELAXED, AG) - tgt) < 0)
      __builtin_amdgcn_s_sleep(1);
  }
  __syncthreads();
}
// poll own replica line (<=8 pollers per line)
__device__ __forceinline__ void wait_epoch(unsigned* line, unsigned epoch) {
  if (threadIdx.x == 0) {
    while ((int)(__hip_atomic_load(line, __ATOMIC_RELAXED, AG) - epoch) < 0)
      __builtin_amdgcn_s_sleep(1);
  }
  __syncthreads();
}
__device__ __forceinline__ void wr2(float* d, ull v) {
  d[0] = __uint_as_float((unsigned)v);
  d[1] = __uint_as_float((unsigned)(v >> 32));
}
__device__ __forceinline__ float act_apply(int act, float v) {
  if (act == 0) {  // jax.nn.gelu (tanh approx)
    float v3 = v * v * v;
    return 0.5f * v * (1.0f + tanhf(0.7978845608028654f * (v + 0.044715f * v3)));
  }
  if (act == 1) return tanhf(v);
  return v;
}

// stage signal: all callers did {stores; fence_vm(); __syncthreads();} first.
// tid0 bumps stageCnt; if it was the bcT-th arrival, wave0 broadcasts epoch
// to 64 replica lines (one store per lane).
__device__ __forceinline__ void stage_signal(unsigned* stageCnt, unsigned bcT,
                                             unsigned* flag, unsigned epoch,
                                             unsigned* sflag) {
  const int tid = threadIdx.x;
  if (tid == 0) {
    unsigned old = __hip_atomic_fetch_add(stageCnt, 1u, __ATOMIC_RELAXED, AG);
    *sflag = (bcT && old == bcT - 1) ? 1u : 0u;
  }
  __syncthreads();
  if (*sflag) {
    if (tid < 64) __hip_atomic_store(flag + tid * 16, epoch, __ATOMIC_RELAXED, AG);
  }
  __syncthreads();
}

// ---------------- P4: rows=4 matmul stage -------------------------------
// 64-col tile, K-chunk [k0,k0+chunk). Internal 4-way K split over waves.
// KC>1: partial + last-arriver (cumulative kcTgt) deterministic reduce.
// bias may be nullptr (treated as zero).
template <int KC, class ZL8, class ST>
__device__ void p4(const float* __restrict__ W, int ldw, const float* __restrict__ bias,
                   int c0, int k0, int chunk, int act, int kc, unsigned kcTgt,
                   unsigned* kcCnt, float* part,
                   unsigned* stageCnt, unsigned bcT, unsigned* flag, unsigned epoch,
                   float* lds, unsigned* sflag, ZL8&& zl8, ST&& store) {
  const int tid = threadIdx.x;
  __syncthreads();  // protect LDS reuse across stages
  const int cp = chunk >> 1;  // pairs per row
  for (int i = tid; i < 4 * cp; i += 256) {
    int b = i / cp, kp = i - b * cp;
    ull v = zl8(b, (k0 >> 1) + kp);
    wr2(&lds[b * chunk + 2 * kp], v);
  }
  __syncthreads();
  const int j = tid & 63, kq = tid >> 6;
  const int sub = chunk >> 2;
  float a0 = 0.f, a1 = 0.f, a2 = 0.f, a3 = 0.f;
  const float* wp = W + (size_t)(k0 + kq * sub) * ldw + (c0 + j);
  const float* z0 = lds + kq * sub;
  const float* z1 = z0 + chunk;
  const float* z2 = z1 + chunk;
  const float* z3 = z2 + chunk;
#pragma unroll 16
  for (int kk = 0; kk < sub; ++kk) {
    float wv = wp[(size_t)kk * ldw];
    a0 = fmaf(z0[kk], wv, a0);
    a1 = fmaf(z1[kk], wv, a1);
    a2 = fmaf(z2[kk], wv, a2);
    a3 = fmaf(z3[kk], wv, a3);
  }
  __syncthreads();
  float* red = lds;  // [4q][64j][4b]
  red[tid * 4 + 0] = a0; red[tid * 4 + 1] = a1;
  red[tid * 4 + 2] = a2; red[tid * 4 + 3] = a3;
  __syncthreads();
  const int jj = tid & 63, bb = tid >> 6;
  float v = red[jj * 4 + bb] + red[256 + jj * 4 + bb] +
            red[512 + jj * 4 + bb] + red[768 + jj * 4 + bb];
  if constexpr (KC == 1) {
    if (bias) v += bias[c0 + jj];
    v = act_apply(act, v);
    store(bb, c0 + jj, v);
    fence_vm();
    __syncthreads();
    stage_signal(stageCnt, bcT, flag, epoch, sflag);
  } else {
    st4(&part[kc * 256 + jj * 4 + bb], v);
    fence_vm();
    __syncthreads();
    if (tid == 0) {
      unsigned old = __hip_atomic_fetch_add(kcCnt, 1u, __ATOMIC_RELAXED, AG);
      *sflag = (old == kcTgt - 1) ? 1u : 0u;
    }
    __syncthreads();
    if (*sflag) {
      float s = 0.f;
#pragma unroll
      for (int q = 0; q < KC; ++q) s += ld4(&part[q * 256 + jj * 4 + bb]);
      if (bias) s += bias[c0 + jj];
      s = act_apply(act, s);
      store(bb, c0 + jj, s);
      fence_vm();
      __syncthreads();
      stage_signal(stageCnt, bcT, flag, epoch, sflag);
    }
  }
  __syncthreads();
}

// ---------------- P64: rows=64 tiled GEMM stage -------------------------
template <int KC, class ZL8, class ST>
__device__ void p64(const float* __restrict__ W, int ldw, const float* __restrict__ bias,
                    int c0, int k0, int k1, int act, int kc, unsigned kcTgt,
                    unsigned* kcCnt, float* part,
                    unsigned* stageCnt, unsigned bcT, unsigned* flag, unsigned epoch,
                    float* lds, unsigned* sflag, ZL8&& zl8, ST&& store) {
  const int tid = threadIdx.x;
  const int tj = tid & 15, tr = tid >> 4;
  float acc[4][4];
#pragma unroll
  for (int r = 0; r < 4; ++r)
#pragma unroll
    for (int c = 0; c < 4; ++c) acc[r][c] = 0.f;
  float* Wl = lds;            // [64][68]
  float* Zl = lds + 64 * 68;  // [64][65]
  const int wk = tid >> 2, wc = (tid & 3) * 16;
  const int r1 = tid >> 3, c8 = tid & 7;
  for (int kb = k0; kb < k1; kb += 64) {
    __syncthreads();
    {  // W: normal (cached) loads, 64B/thread
      const float* src = W + (size_t)(kb + wk) * ldw + c0 + wc;
      float4 w0 = *(const float4*)(src);
      float4 w1 = *(const float4*)(src + 4);
      float4 w2 = *(const float4*)(src + 8);
      float4 w3 = *(const float4*)(src + 12);
      *(float4*)&Wl[wk * 68 + wc + 0]  = w0;
      *(float4*)&Wl[wk * 68 + wc + 4]  = w1;
      *(float4*)&Wl[wk * 68 + wc + 8]  = w2;
      *(float4*)&Wl[wk * 68 + wc + 12] = w3;
    }
    {  // Z: coherent pair loads; 8 lanes cover one 64B line per instr
      ull v[8];
#pragma unroll
      for (int q = 0; q < 8; ++q) {
        int row = (q < 4) ? r1 : 32 + r1;
        int kp = c8 + 8 * (q & 3);
        v[q] = zl8(row, (kb >> 1) + kp);
      }
#pragma unroll
      for (int q = 0; q < 8; ++q) {
        int row = (q < 4) ? r1 : 32 + r1;
        int kp = c8 + 8 * (q & 3);
        wr2(&Zl[row * 65 + 2 * kp], v[q]);
      }
    }
    __syncthreads();
#pragma unroll 4
    for (int kk = 0; kk < 64; ++kk) {
      float4 w4 = *(float4*)&Wl[kk * 68 + tj * 4];
      float zr0 = Zl[(tr * 4 + 0) * 65 + kk];
      float zr1 = Zl[(tr * 4 + 1) * 65 + kk];
      float zr2 = Zl[(tr * 4 + 2) * 65 + kk];
      float zr3 = Zl[(tr * 4 + 3) * 65 + kk];
      acc[0][0] = fmaf(zr0, w4.x, acc[0][0]); acc[0][1] = fmaf(zr0, w4.y, acc[0][1]);
      acc[0][2] = fmaf(zr0, w4.z, acc[0][2]); acc[0][3] = fmaf(zr0, w4.w, acc[0][3]);
      acc[1][0] = fmaf(zr1, w4.x, acc[1][0]); acc[1][1] = fmaf(zr1, w4.y, acc[1][1]);
      acc[1][2] = fmaf(zr1, w4.z, acc[1][2]); acc[1][3] = fmaf(zr1, w4.w, acc[1][3]);
      acc[2][0] = fmaf(zr2, w4.x, acc[2][0]); acc[2][1] = fmaf(zr2, w4.y, acc[2][1]);
      acc[2][2] = fmaf(zr2, w4.z, acc[2][2]); acc[2][3] = fmaf(zr2, w4.w, acc[2][3]);
      acc[3][0] = fmaf(zr3, w4.x, acc[3][0]); acc[3][1] = fmaf(zr3, w4.y, acc[3][1]);
      acc[3][2] = fmaf(zr3, w4.z, acc[3][2]); acc[3][3] = fmaf(zr3, w4.w, acc[3][3]);
    }
  }
  __syncthreads();
  if constexpr (KC == 1) {
#pragma unroll
    for (int r = 0; r < 4; ++r)
#pragma unroll
      for (int c = 0; c < 4; ++c) {
        int col = c0 + tj * 4 + c;
        float v = acc[r][c] + (bias ? bias[col] : 0.f);
        v = act_apply(act, v);
        store(tr * 4 + r, col, v);
      }
    fence_vm();
    __syncthreads();
    stage_signal(stageCnt, bcT, flag, epoch, sflag);
  } else {
    float* pp = part + kc * 4096;
#pragma unroll
    for (int r = 0; r < 4; ++r)
#pragma unroll
      for (int c = 0; c < 4; ++c)
        st4(&pp[(tr * 4 + r) * 64 + tj * 4 + c], acc[r][c]);
    fence_vm();
    __syncthreads();
    if (tid == 0) {
      unsigned old = __hip_atomic_fetch_add(kcCnt, 1u, __ATOMIC_RELAXED, AG);
      *sflag = (old == kcTgt - 1) ? 1u : 0u;
    }
    __syncthreads();
    if (*sflag) {
      for (int r = 0; r < 4; ++r)
        for (int c = 0; c < 4; ++c) {
          int idx = (tr * 4 + r) * 64 + tj * 4 + c;
          float s = 0.f;
#pragma unroll
          for (int q = 0; q < KC; ++q) s += ld4(&part[q * 4096 + idx]);
          int col = c0 + tj * 4 + c;
          if (bias) s += bias[col];
          s = act_apply(act, s);
          store(tr * 4 + r, col, s);
        }
      fence_vm();
      __syncthreads();
      stage_signal(stageCnt, bcT, flag, epoch, sflag);
    }
  }
  __syncthreads();
}

struct P {
  const float *x;
  const float *e0W0, *e0b0, *e0W1, *e0b1, *e0W2, *e0b2;
  const float *erW0, *erb0, *erW1, *erb1, *erW2, *erb2;
  const float *ffW0, *ffb0, *ffW1, *ffb1;
  const float *dW0, *db0, *dWh, *dbh, *dWo, *dbo;
  float *S, *h1, *h2, *g, *eo, *hd_pre, *hd0, *hd1, *dob, *pF2, *pD;
  unsigned* cnt;
  float* out;
};

// S layout: S[r][t][e][b][512]
#define S_IDX(r, t, e, b) ((size_t)((((r)*16 + (t)) * 16 + (e)) * 4 + (b)) * 512)

// counter map: each logical counter occupies its own 64B line (16 u32).
#define C_A 0        // aT[e*4+lvl]   (64)
#define C_B 64       // bT            (64)
#define C_C 128      // cT            (64)
#define C_FFG 192    // ffg[e]        (16)
#define C_KF2 208    // kcF2[e*8+ct]  (128)
#define C_FFO 336    // ffo           (1)
#define C_DC 344     // dcnt[6]       (6)
#define C_KD 352     // kcD[32]       (32)
#define C_KDO 384    // kcDo[16]      (16)
#define C_KL0 400    // kcL0[tile]    (32)
#define C_L0C 432    // L0a done      (1)
#define C_FFLAG 440  // flagFF        (64 lines)
#define C_L0FLAG 504 // flagL0a       (64 lines)
#define C_OFLAG 568  // flagOut       (64 lines)
#define C_DFLAG 632  // flagD[5]      (5*64 lines, end 952)

__global__ __launch_bounds__(256, 2) void hrnn(P p) {
  __shared__ __align__(16) float lds[64 * 68 + 64 * 65];
  __shared__ unsigned sflag;
  const int w = blockIdx.x;
  const int e = w & 15, lvl = (w >> 4) & 3, sub = w >> 6;  // encoder roles
  auto cptr = [&](int i) { return p.cnt + (size_t)i * 16; };
  unsigned* myline_ff = cptr(C_FFLAG + (w & 63));
  unsigned* myline_l0 = cptr(C_L0FLAG + (w & 63));
  unsigned* myline_out = cptr(C_OFLAG + (w & 63));

  // ======== ENCODERS: wavefront over (lvl,t); 8 WGs per (e,lvl) ==========
  {
    const float *W0, *B0, *W1, *B1, *W2, *B2;
    int K0;
    if (lvl == 0) {
      W0 = p.e0W0 + (size_t)e * 544 * 512; B0 = p.e0b0 + e * 512;
      W1 = p.e0W1 + (size_t)e * 262144;    B1 = p.e0b1 + e * 512;
      W2 = p.e0W2 + (size_t)e * 262144;    B2 = p.e0b2 + e * 512;
      K0 = 544;
    } else {
      int ri = (lvl - 1) * 16 + e;
      W0 = p.erW0 + (size_t)ri * 524288; B0 = p.erb0 + (size_t)ri * 512;
      W1 = p.erW1 + (size_t)ri * 262144; B1 = p.erb1 + (size_t)ri * 512;
      W2 = p.erW2 + (size_t)ri * 262144; B2 = p.erb2 + (size_t)ri * 512;
      K0 = 1024;
    }
    unsigned* aT = cptr(C_A + e * 4 + lvl);
    unsigned* bT = cptr(C_B + e * 4 + lvl);
    unsigned* cT = cptr(C_C + e * 4 + lvl);
    float* h1 = p.h1 + (size_t)(e * 4 + lvl) * 4 * 512;
    float* h2 = p.h2 + (size_t)(e * 4 + lvl) * 4 * 512;
    for (int t = 0; t < 16; ++t) {
      if (t) waitge(cT, 8u * t);
      if (lvl) waitge(cptr(C_C + e * 4 + lvl - 1), 8u * (t + 1));
      {  // stage A
        const float* x = p.x; const float* S = p.S;
        const int tt = t, ee = e, rr = lvl;
        auto zl = [=](int b, int kp) -> ull {
          if (rr == 0) {
            if (kp < 16) return *(const ull*)(x + ((b * 16 + tt) * 32 + 2 * kp));
            return tt ? ld8(S + S_IDX(0, tt - 1, ee, b) + 2 * kp - 32) : 0ull;
          } else {
            if (kp < 256) return ld8(S + S_IDX(rr - 1, tt, ee, b) + 2 * kp);
            return tt ? ld8(S + S_IDX(rr, tt - 1, ee, b) + 2 * kp - 512) : 0ull;
          }
        };
        auto st = [=](int b, int col, float v) { st4(h1 + b * 512 + col, v); };
        p4<1>(W0, 512, B0, sub * 64, 0, K0, 0, 0, 0, nullptr, nullptr,
              aT, 0, nullptr, 0, lds, &sflag, zl, st);
      }
      waitge(aT, 8u * (t + 1));
      {  // stage B
        auto zl = [=](int b, int kp) -> ull { return ld8(h1 + b * 512 + 2 * kp); };
        auto st = [=](int b, int col, float v) { st4(h2 + b * 512 + col, v); };
        p4<1>(W1, 512, B1, sub * 64, 0, 512, 0, 0, 0, nullptr, nullptr,
              bT, 0, nullptr, 0, lds, &sflag, zl, st);
      }
      waitge(bT, 8u * (t + 1));
      {  // stage C
        float* S = p.S; const int tt = t, ee = e, rr = lvl;
        auto zl = [=](int b, int kp) -> ull { return ld8(h2 + b * 512 + 2 * kp); };
        auto st = [=](int b, int col, float v) { st4(S + S_IDX(rr, tt, ee, b) + col, v); };
        p4<1>(W2, 512, B2, sub * 64, 0, 512, 1, 0, 0, nullptr, nullptr,
              cT, 0, nullptr, 0, lds, &sflag, zl, st);
      }
    }
  }

  // ======== FF1: rows=64 (t,b), K=2048, 32 col-tiles per e ================
  for (int r = 0; r < 4; ++r) waitge(cptr(C_C + e * 4 + r), 128u);
  {
    const float* S = p.S; const int ee = e;
    auto zl = [=](int row, int kp) -> ull {
      int k = 2 * kp, tt = row >> 2, b = row & 3, seg = k >> 9;
      return ld8(S + S_IDX(seg, tt, ee, b) + (k & 511));
    };
    float* g = p.g + (size_t)e * 131072;
    auto st = [=](int row, int col, float v) { st4(g + (size_t)row * 2048 + col, v); };
    int slot = w >> 4;
    p64<1>(p.ffW0 + (size_t)e * 4194304, 2048, p.ffb0 + e * 2048, slot * 64, 0, 2048,
           0, 0, 0, nullptr, nullptr, cptr(C_FFG + e), 0, nullptr, 0,
           lds, &sflag, zl, st);
  }
  waitge(cptr(C_FFG + e), 32u);
  // ======== FF2: K=2048 split 4; completion broadcast to flagFF ===========
  {
    int ct = w >> 6, kc2 = (w >> 4) & 3;
    const float* g = p.g + (size_t)e * 131072;
    auto zl = [=](int row, int kp) -> ull { return ld8(g + (size_t)row * 2048 + 2 * kp); };
    float* eo = p.eo; const int ee = e;
    auto st = [=](int row, int col, float v) {
      int tt = row >> 2, b = row & 3;
      st4(eo + (size_t)((tt * 16 + ee) * 4 + b) * 512 + col, v);
    };
    p64<4>(p.ffW1 + (size_t)e * 1048576, 512, p.ffb1 + e * 512, ct * 64,
           kc2 * 512, (kc2 + 1) * 512, 2, kc2, 4u,
           cptr(C_KF2 + e * 8 + ct), p.pF2 + (size_t)(e * 8 + ct) * 16384,
           cptr(C_FFO), 128u, cptr(C_FFLAG), 1u, lds, &sflag, zl, st);
  }

  // ======== L0a: batched eo @ dW0[:8192] over all 64 (t,b) rows ===========
  // state-independent part of decoder layer 0, weights read ONCE (67 MB)
  wait_epoch(myline_ff, 1u);
  const int tile = w >> 4, kD = w & 15;   // 32 tiles x 16 kc
  const int tileO = w >> 5, kO = w & 31;  // out: 16 tiles x 32 kc
  {
    const float* eo = p.eo;
    auto zl = [=](int row, int kp) -> ull {
      int k = 2 * kp, tt = row >> 2, b = row & 3, e2 = k >> 9;
      return ld8(eo + (size_t)((tt * 16 + e2) * 4 + b) * 512 + (k & 511));
    };
    float* hp = p.hd_pre;
    auto st = [=](int row, int col, float v) { st4(hp + (size_t)row * 2048 + col, v); };
    p64<16>(p.dW0, 2048, p.db0, tile * 64, kD * 512, (kD + 1) * 512, 2, kD, 16u,
            cptr(C_KL0 + tile), p.pF2 + (size_t)tile * 65536,
            cptr(C_L0C), 32u, cptr(C_L0FLAG), 1u, lds, &sflag, zl, st);
  }
  wait_epoch(myline_l0, 1u);

  // ======== DECODER: sequential over t; serial K now only 1024 ===========
  {
    const float* dW0b = p.dW0 + (size_t)8192 * 2048;  // state rows of dW0
    for (int t = 0; t < 16; ++t) {
      if (t) wait_epoch(myline_out, (unsigned)t);
      {  // L0b: state part K=1024 + hd_pre (eo part + bias) -> gelu
        const float* dob = p.dob; const int tt = t;
        auto zl = [=](int b, int kpg) -> ull {
          return tt ? ld8(dob + b * 1024 + 2 * kpg) : 0ull;
        };
        const float* hp = p.hd_pre; float* hd = p.hd0;
        auto st = [=](int b, int col, float v) {
          v += ld4(hp + (size_t)(tt * 4 + b) * 2048 + col);
          v = act_apply(0, v);
          st4(hd + b * 2048 + col, v);
        };
        p4<16>(dW0b, 2048, nullptr, tile * 64, kD * 64, 64, 2, kD, 80u * t + 16u,
               cptr(C_KD + tile), p.pD + (size_t)tile * 4096,
               cptr(C_DC + 0), 32u * (t + 1), cptr(C_DFLAG + 0 * 64), (unsigned)(t + 1),
               lds, &sflag, zl, st);
      }
      for (int l = 1; l <= 4; ++l) {
        wait_epoch(cptr(C_DFLAG + (l - 1) * 64 + (w & 63)), (unsigned)(t + 1));
        const float* hin = (l & 1) ? p.hd0 : p.hd1;
        float* hout = (l & 1) ? p.hd1 : p.hd0;
        auto zl = [=](int b, int kp) -> ull { return ld8(hin + b * 2048 + 2 * kp); };
        auto st = [=](int b, int col, float v) { st4(hout + b * 2048 + col, v); };
        p4<16>(p.dWh + (size_t)(l - 1) * 4194304, 2048, p.dbh + (size_t)(l - 1) * 2048,
               tile * 64, kD * 128, 128, 0, kD, 80u * t + 16u * (l + 1),
               cptr(C_KD + tile), p.pD + (size_t)tile * 4096,
               cptr(C_DC + l), 32u * (t + 1), cptr(C_DFLAG + l * 64), (unsigned)(t + 1),
               lds, &sflag, zl, st);
      }
      wait_epoch(cptr(C_DFLAG + 4 * 64 + (w & 63)), (unsigned)(t + 1));
      {  // out layer: tanh -> d_out and dec state
        const float* hin = p.hd0; float* dob = p.dob; float* outp = p.out; const int tt = t;
        auto zl = [=](int b, int kp) -> ull { return ld8(hin + b * 2048 + 2 * kp); };
        auto st = [=](int b, int col, float v) {
          outp[(size_t)(b * 16 + tt) * 1024 + col] = v;  // host-visible
          st4(dob + b * 1024 + col, v);
        };
        p4<32>(p.dWo, 1024, p.dbo, tileO * 64, kO * 64, 64, 1, kO, 32u * (t + 1),
               cptr(C_KDO + tileO), p.pD + (size_t)tileO * 8192,
               cptr(C_DC + 5), 16u * (t + 1), cptr(C_OFLAG), (unsigned)(t + 1),
               lds, &sflag, zl, st);
      }
    }
  }
}

extern "C" void kernel_launch(void* const* d_in, const int* in_sizes, int n_in,
                              void* d_out, int out_size, void* d_ws, size_t ws_size,
                              hipStream_t stream) {
  hipMemsetAsync(d_ws, 0, 65536, stream);  // zero padded counters + flags

  P p;
  p.x    = (const float*)d_in[0];
  p.e0W0 = (const float*)d_in[1];  p.e0b0 = (const float*)d_in[2];
  p.e0W1 = (const float*)d_in[3];  p.e0b1 = (const float*)d_in[4];
  p.e0W2 = (const float*)d_in[5];  p.e0b2 = (const float*)d_in[6];
  p.erW0 = (const float*)d_in[7];  p.erb0 = (const float*)d_in[8];
  p.erW1 = (const float*)d_in[9];  p.erb1 = (const float*)d_in[10];
  p.erW2 = (const float*)d_in[11]; p.erb2 = (const float*)d_in[12];
  p.ffW0 = (const float*)d_in[13]; p.ffb0 = (const float*)d_in[14];
  p.ffW1 = (const float*)d_in[15]; p.ffb1 = (const float*)d_in[16];
  p.dW0  = (const float*)d_in[17]; p.db0  = (const float*)d_in[18];
  p.dWh  = (const float*)d_in[19]; p.dbh  = (const float*)d_in[20];
  p.dWo  = (const float*)d_in[21]; p.dbo  = (const float*)d_in[22];

  float* base = (float*)((char*)d_ws + 65536);
  p.S      = base; base += 2097152;  // 4*16*16*4*512
  p.h1     = base; base += 131072;   // 16*4 cells * 4*512
  p.h2     = base; base += 131072;
  p.g      = base; base += 2097152;  // 16*64*2048
  p.eo     = base; base += 524288;   // 16*16*4*512
  p.hd_pre = base; base += 131072;   // 64*2048
  p.hd0    = base; base += 8192;
  p.hd1    = base; base += 8192;
  p.dob    = base; base += 4096;
  p.pF2    = base; base += 2097152;  // FF2 partials; reused by L0a (after FF done)
  p.pD     = base; base += 131072;   // 32*16*256 == 16*32*256

  p.cnt = (unsigned*)d_ws;
  p.out = (float*)d_out;

  hipLaunchKernelGGL(hrnn, dim3(512), dim3(256), 0, stream, p);
}

// Round 8
// 1994.735 us; speedup vs baseline: 1.5668x; 1.0651x over previous
//
#include <hip/hip_runtime.h>
#include <math.h>
#include <stdint.h>

#define AG __HIP_MEMORY_SCOPE_AGENT
typedef unsigned long long ull;

// ---- cross-XCD-coherent data ops (per-address at MALL, no cache maintenance)
__device__ __forceinline__ float ld4(const float* p) {
  return __hip_atomic_load(p, __ATOMIC_RELAXED, AG);
}
__device__ __forceinline__ void st4(float* p, float v) {
  __hip_atomic_store(p, v, __ATOMIC_RELAXED, AG);
}
__device__ __forceinline__ ull ld8(const float* p) {
  return __hip_atomic_load((const ull*)p, __ATOMIC_RELAXED, AG);
}
__device__ __forceinline__ void fence_vm() {
  asm volatile("s_waitcnt vmcnt(0)" ::: "memory");
}
__device__ __forceinline__ void waitge(unsigned* c, unsigned tgt) {
  if (threadIdx.x == 0) {
    while ((int)(__hip_atomic_load(c, __ATOMIC_RELAXED, AG) - tgt) < 0)
      __builtin_amdgcn_s_sleep(1);
  }
  __syncthreads();
}
// poll own replica line (<=8 pollers per line)
__device__ __forceinline__ void wait_epoch(unsigned* line, unsigned epoch) {
  if (threadIdx.x == 0) {
    while ((int)(__hip_atomic_load(line, __ATOMIC_RELAXED, AG) - epoch) < 0)
      __builtin_amdgcn_s_sleep(1);
  }
  __syncthreads();
}
__device__ __forceinline__ void wr2(float* d, ull v) {
  d[0] = __uint_as_float((unsigned)v);
  d[1] = __uint_as_float((unsigned)(v >> 32));
}
__device__ __forceinline__ float act_apply(int act, float v) {
  if (act == 0) {  // jax.nn.gelu (tanh approx)
    float v3 = v * v * v;
    return 0.5f * v * (1.0f + tanhf(0.7978845608028654f * (v + 0.044715f * v3)));
  }
  if (act == 1) return tanhf(v);
  return v;
}

// stage signal: all callers did {stores; fence_vm(); __syncthreads();} first.
// tid0 bumps stageCnt; if it was the bcT-th arrival, wave0 broadcasts epoch
// to 64 replica lines (one store per lane).
__device__ __forceinline__ void stage_signal(unsigned* stageCnt, unsigned bcT,
                                             unsigned* flag, unsigned epoch,
                                             unsigned* sflag) {
  const int tid = threadIdx.x;
  if (tid == 0) {
    unsigned old = __hip_atomic_fetch_add(stageCnt, 1u, __ATOMIC_RELAXED, AG);
    *sflag = (bcT && old == bcT - 1) ? 1u : 0u;
  }
  __syncthreads();
  if (*sflag) {
    if (tid < 64) __hip_atomic_store(flag + tid * 16, epoch, __ATOMIC_RELAXED, AG);
  }
  __syncthreads();
}

// ---------------- P4: rows=4 matmul stage, fat float4 W loads -----------
// 64-col tile, K-chunk [k0,k0+chunk). Lane (q=wave, kg=lane>>4, j4=lane&15)
// loads float4 W[k][c0+4*j4..+3] for k = q*sub + 4*kk + kg -> 1KB/wave-instr
// (4x bytes-in-flight vs scalar). Intra-WG reduce over 16 (q,kg) groups via
// one LDS pass (no extra cross-WG hops). KC>1: partial + last-arriver
// (cumulative kcTgt) deterministic reduce. bias may be nullptr.
template <int KC, class ZL8, class ST>
__device__ void p4(const float* __restrict__ W, int ldw, const float* __restrict__ bias,
                   int c0, int k0, int chunk, int act, int kc, unsigned kcTgt,
                   unsigned* kcCnt, float* part,
                   unsigned* stageCnt, unsigned bcT, unsigned* flag, unsigned epoch,
                   float* lds, unsigned* sflag, ZL8&& zl8, ST&& store) {
  const int tid = threadIdx.x;
  __syncthreads();  // protect LDS reuse across stages
  const int cp = chunk >> 1;  // pairs per row
  for (int i = tid; i < 4 * cp; i += 256) {
    int b = i / cp, kp = i - b * cp;
    wr2(&lds[b * chunk + 2 * kp], zl8(b, (k0 >> 1) + kp));
  }
  __syncthreads();
  const int q = tid >> 6, lane = tid & 63;
  const int kg = lane >> 4, j4 = lane & 15;
  const int sub = chunk >> 2;
  const int nk = sub >> 2;
  float acc[4][4];
#pragma unroll
  for (int r = 0; r < 4; ++r)
#pragma unroll
    for (int c = 0; c < 4; ++c) acc[r][c] = 0.f;
  const float* wp = W + (size_t)(k0 + q * sub + kg) * ldw + (c0 + 4 * j4);
  const float* zq = lds + q * sub + kg;
#pragma unroll 16
  for (int kk = 0; kk < nk; ++kk) {
    float4 w4 = *(const float4*)(wp + (size_t)(4 * kk) * ldw);
    float z0 = zq[4 * kk];
    float z1 = zq[chunk + 4 * kk];
    float z2 = zq[2 * chunk + 4 * kk];
    float z3 = zq[3 * chunk + 4 * kk];
    acc[0][0] = fmaf(z0, w4.x, acc[0][0]); acc[0][1] = fmaf(z0, w4.y, acc[0][1]);
    acc[0][2] = fmaf(z0, w4.z, acc[0][2]); acc[0][3] = fmaf(z0, w4.w, acc[0][3]);
    acc[1][0] = fmaf(z1, w4.x, acc[1][0]); acc[1][1] = fmaf(z1, w4.y, acc[1][1]);
    acc[1][2] = fmaf(z1, w4.z, acc[1][2]); acc[1][3] = fmaf(z1, w4.w, acc[1][3]);
    acc[2][0] = fmaf(z2, w4.x, acc[2][0]); acc[2][1] = fmaf(z2, w4.y, acc[2][1]);
    acc[2][2] = fmaf(z2, w4.z, acc[2][2]); acc[2][3] = fmaf(z2, w4.w, acc[2][3]);
    acc[3][0] = fmaf(z3, w4.x, acc[3][0]); acc[3][1] = fmaf(z3, w4.y, acc[3][1]);
    acc[3][2] = fmaf(z3, w4.z, acc[3][2]); acc[3][3] = fmaf(z3, w4.w, acc[3][3]);
  }
  __syncthreads();  // z dead; reuse lds as red[16 grp][16 j4][4 b][4 c]
  float* red = lds;
  float* myred = red + (q * 4 + kg) * 256 + j4 * 16;
#pragma unroll
  for (int b = 0; b < 4; ++b) {
    float4 v4;
    v4.x = acc[b][0]; v4.y = acc[b][1]; v4.z = acc[b][2]; v4.w = acc[b][3];
    *(float4*)(myred + b * 4) = v4;
  }
  __syncthreads();
  // thread tid -> output (col = c0 + 4*(tid>>4) + (tid&3), b = (tid>>2)&3)
  const int j4o = tid >> 4, bb = (tid >> 2) & 3, cc = tid & 3;
  const int oj = 4 * j4o + cc;
  float v = 0.f;
#pragma unroll
  for (int g = 0; g < 16; ++g) v += red[g * 256 + j4o * 16 + bb * 4 + cc];
  if constexpr (KC == 1) {
    if (bias) v += bias[c0 + oj];
    v = act_apply(act, v);
    store(bb, c0 + oj, v);
    fence_vm();
    __syncthreads();
    stage_signal(stageCnt, bcT, flag, epoch, sflag);
  } else {
    st4(&part[kc * 256 + oj * 4 + bb], v);
    fence_vm();
    __syncthreads();
    if (tid == 0) {
      unsigned old = __hip_atomic_fetch_add(kcCnt, 1u, __ATOMIC_RELAXED, AG);
      *sflag = (old == kcTgt - 1) ? 1u : 0u;
    }
    __syncthreads();
    if (*sflag) {
      float s = 0.f;
#pragma unroll
      for (int g = 0; g < KC; ++g) s += ld4(&part[g * 256 + oj * 4 + bb]);
      if (bias) s += bias[c0 + oj];
      s = act_apply(act, s);
      store(bb, c0 + oj, s);
      fence_vm();
      __syncthreads();
      stage_signal(stageCnt, bcT, flag, epoch, sflag);
    }
  }
  __syncthreads();
}

// ---------------- P64: rows=64 tiled GEMM stage -------------------------
template <int KC, class ZL8, class ST>
__device__ void p64(const float* __restrict__ W, int ldw, const float* __restrict__ bias,
                    int c0, int k0, int k1, int act, int kc, unsigned kcTgt,
                    unsigned* kcCnt, float* part,
                    unsigned* stageCnt, unsigned bcT, unsigned* flag, unsigned epoch,
                    float* lds, unsigned* sflag, ZL8&& zl8, ST&& store) {
  const int tid = threadIdx.x;
  const int tj = tid & 15, tr = tid >> 4;
  float acc[4][4];
#pragma unroll
  for (int r = 0; r < 4; ++r)
#pragma unroll
    for (int c = 0; c < 4; ++c) acc[r][c] = 0.f;
  float* Wl = lds;            // [64][68]
  float* Zl = lds + 64 * 68;  // [64][65]
  const int wk = tid >> 2, wc = (tid & 3) * 16;
  const int r1 = tid >> 3, c8 = tid & 7;
  for (int kb = k0; kb < k1; kb += 64) {
    __syncthreads();
    {  // W: normal (cached) loads, 64B/thread
      const float* src = W + (size_t)(kb + wk) * ldw + c0 + wc;
      float4 w0 = *(const float4*)(src);
      float4 w1 = *(const float4*)(src + 4);
      float4 w2 = *(const float4*)(src + 8);
      float4 w3 = *(const float4*)(src + 12);
      *(float4*)&Wl[wk * 68 + wc + 0]  = w0;
      *(float4*)&Wl[wk * 68 + wc + 4]  = w1;
      *(float4*)&Wl[wk * 68 + wc + 8]  = w2;
      *(float4*)&Wl[wk * 68 + wc + 12] = w3;
    }
    {  // Z: coherent pair loads; 8 lanes cover one 64B line per instr
      ull v[8];
#pragma unroll
      for (int q = 0; q < 8; ++q) {
        int row = (q < 4) ? r1 : 32 + r1;
        int kp = c8 + 8 * (q & 3);
        v[q] = zl8(row, (kb >> 1) + kp);
      }
#pragma unroll
      for (int q = 0; q < 8; ++q) {
        int row = (q < 4) ? r1 : 32 + r1;
        int kp = c8 + 8 * (q & 3);
        wr2(&Zl[row * 65 + 2 * kp], v[q]);
      }
    }
    __syncthreads();
#pragma unroll 4
    for (int kk = 0; kk < 64; ++kk) {
      float4 w4 = *(float4*)&Wl[kk * 68 + tj * 4];
      float zr0 = Zl[(tr * 4 + 0) * 65 + kk];
      float zr1 = Zl[(tr * 4 + 1) * 65 + kk];
      float zr2 = Zl[(tr * 4 + 2) * 65 + kk];
      float zr3 = Zl[(tr * 4 + 3) * 65 + kk];
      acc[0][0] = fmaf(zr0, w4.x, acc[0][0]); acc[0][1] = fmaf(zr0, w4.y, acc[0][1]);
      acc[0][2] = fmaf(zr0, w4.z, acc[0][2]); acc[0][3] = fmaf(zr0, w4.w, acc[0][3]);
      acc[1][0] = fmaf(zr1, w4.x, acc[1][0]); acc[1][1] = fmaf(zr1, w4.y, acc[1][1]);
      acc[1][2] = fmaf(zr1, w4.z, acc[1][2]); acc[1][3] = fmaf(zr1, w4.w, acc[1][3]);
      acc[2][0] = fmaf(zr2, w4.x, acc[2][0]); acc[2][1] = fmaf(zr2, w4.y, acc[2][1]);
      acc[2][2] = fmaf(zr2, w4.z, acc[2][2]); acc[2][3] = fmaf(zr2, w4.w, acc[2][3]);
      acc[3][0] = fmaf(zr3, w4.x, acc[3][0]); acc[3][1] = fmaf(zr3, w4.y, acc[3][1]);
      acc[3][2] = fmaf(zr3, w4.z, acc[3][2]); acc[3][3] = fmaf(zr3, w4.w, acc[3][3]);
    }
  }
  __syncthreads();
  if constexpr (KC == 1) {
#pragma unroll
    for (int r = 0; r < 4; ++r)
#pragma unroll
      for (int c = 0; c < 4; ++c) {
        int col = c0 + tj * 4 + c;
        float v = acc[r][c] + (bias ? bias[col] : 0.f);
        v = act_apply(act, v);
        store(tr * 4 + r, col, v);
      }
    fence_vm();
    __syncthreads();
    stage_signal(stageCnt, bcT, flag, epoch, sflag);
  } else {
    float* pp = part + kc * 4096;
#pragma unroll
    for (int r = 0; r < 4; ++r)
#pragma unroll
      for (int c = 0; c < 4; ++c)
        st4(&pp[(tr * 4 + r) * 64 + tj * 4 + c], acc[r][c]);
    fence_vm();
    __syncthreads();
    if (tid == 0) {
      unsigned old = __hip_atomic_fetch_add(kcCnt, 1u, __ATOMIC_RELAXED, AG);
      *sflag = (old == kcTgt - 1) ? 1u : 0u;
    }
    __syncthreads();
    if (*sflag) {
      for (int r = 0; r < 4; ++r)
        for (int c = 0; c < 4; ++c) {
          int idx = (tr * 4 + r) * 64 + tj * 4 + c;
          float s = 0.f;
#pragma unroll
          for (int q = 0; q < KC; ++q) s += ld4(&part[q * 4096 + idx]);
          int col = c0 + tj * 4 + c;
          if (bias) s += bias[col];
          s = act_apply(act, s);
          store(tr * 4 + r, col, s);
        }
      fence_vm();
      __syncthreads();
      stage_signal(stageCnt, bcT, flag, epoch, sflag);
    }
  }
  __syncthreads();
}

struct P {
  const float *x;
  const float *e0W0, *e0b0, *e0W1, *e0b1, *e0W2, *e0b2;
  const float *erW0, *erb0, *erW1, *erb1, *erW2, *erb2;
  const float *ffW0, *ffb0, *ffW1, *ffb1;
  const float *dW0, *db0, *dWh, *dbh, *dWo, *dbo;
  float *S, *h1, *h2, *g, *eo, *hd_pre, *hd0, *hd1, *dob, *pF2, *pD;
  unsigned* cnt;
  float* out;
};

// S layout: S[r][t][e][b][512]
#define S_IDX(r, t, e, b) ((size_t)((((r)*16 + (t)) * 16 + (e)) * 4 + (b)) * 512)

// counter map: each logical counter occupies its own 64B line (16 u32).
#define C_A 0        // aT[e*4+lvl]   (64)
#define C_B 64       // bT            (64)
#define C_C 128      // cT            (64)
#define C_FFG 192    // ffg[e]        (16)
#define C_KF2 208    // kcF2[e*8+ct]  (128)
#define C_FFO 336    // ffo           (1)
#define C_DC 344     // dcnt[6]       (6)
#define C_KD 352     // kcD[32]       (32)
#define C_KDO 384    // kcDo[16]      (16)
#define C_KL0 400    // kcL0[tile]    (32)
#define C_L0C 432    // L0a done      (1)
#define C_FFLAG 440  // flagFF        (64 lines)
#define C_L0FLAG 504 // flagL0a       (64 lines)
#define C_OFLAG 568  // flagOut       (64 lines)
#define C_DFLAG 632  // flagD[5]      (5*64 lines, end 952)

__global__ __launch_bounds__(256, 2) void hrnn(P p) {
  __shared__ __align__(16) float lds[64 * 68 + 64 * 65];
  __shared__ unsigned sflag;
  const int w = blockIdx.x;
  const int e = w & 15, lvl = (w >> 4) & 3, sub = w >> 6;  // encoder roles
  auto cptr = [&](int i) { return p.cnt + (size_t)i * 16; };
  unsigned* myline_ff = cptr(C_FFLAG + (w & 63));
  unsigned* myline_l0 = cptr(C_L0FLAG + (w & 63));
  unsigned* myline_out = cptr(C_OFLAG + (w & 63));

  // ======== ENCODERS: wavefront over (lvl,t); 8 WGs per (e,lvl) ==========
  {
    const float *W0, *B0, *W1, *B1, *W2, *B2;
    int K0;
    if (lvl == 0) {
      W0 = p.e0W0 + (size_t)e * 544 * 512; B0 = p.e0b0 + e * 512;
      W1 = p.e0W1 + (size_t)e * 262144;    B1 = p.e0b1 + e * 512;
      W2 = p.e0W2 + (size_t)e * 262144;    B2 = p.e0b2 + e * 512;
      K0 = 544;
    } else {
      int ri = (lvl - 1) * 16 + e;
      W0 = p.erW0 + (size_t)ri * 524288; B0 = p.erb0 + (size_t)ri * 512;
      W1 = p.erW1 + (size_t)ri * 262144; B1 = p.erb1 + (size_t)ri * 512;
      W2 = p.erW2 + (size_t)ri * 262144; B2 = p.erb2 + (size_t)ri * 512;
      K0 = 1024;
    }
    unsigned* aT = cptr(C_A + e * 4 + lvl);
    unsigned* bT = cptr(C_B + e * 4 + lvl);
    unsigned* cT = cptr(C_C + e * 4 + lvl);
    float* h1 = p.h1 + (size_t)(e * 4 + lvl) * 4 * 512;
    float* h2 = p.h2 + (size_t)(e * 4 + lvl) * 4 * 512;
    for (int t = 0; t < 16; ++t) {
      if (t) waitge(cT, 8u * t);
      if (lvl) waitge(cptr(C_C + e * 4 + lvl - 1), 8u * (t + 1));
      {  // stage A
        const float* x = p.x; const float* S = p.S;
        const int tt = t, ee = e, rr = lvl;
        auto zl = [=](int b, int kp) -> ull {
          if (rr == 0) {
            if (kp < 16) return *(const ull*)(x + ((b * 16 + tt) * 32 + 2 * kp));
            return tt ? ld8(S + S_IDX(0, tt - 1, ee, b) + 2 * kp - 32) : 0ull;
          } else {
            if (kp < 256) return ld8(S + S_IDX(rr - 1, tt, ee, b) + 2 * kp);
            return tt ? ld8(S + S_IDX(rr, tt - 1, ee, b) + 2 * kp - 512) : 0ull;
          }
        };
        auto st = [=](int b, int col, float v) { st4(h1 + b * 512 + col, v); };
        p4<1>(W0, 512, B0, sub * 64, 0, K0, 0, 0, 0, nullptr, nullptr,
              aT, 0, nullptr, 0, lds, &sflag, zl, st);
      }
      waitge(aT, 8u * (t + 1));
      {  // stage B
        auto zl = [=](int b, int kp) -> ull { return ld8(h1 + b * 512 + 2 * kp); };
        auto st = [=](int b, int col, float v) { st4(h2 + b * 512 + col, v); };
        p4<1>(W1, 512, B1, sub * 64, 0, 512, 0, 0, 0, nullptr, nullptr,
              bT, 0, nullptr, 0, lds, &sflag, zl, st);
      }
      waitge(bT, 8u * (t + 1));
      {  // stage C
        float* S = p.S; const int tt = t, ee = e, rr = lvl;
        auto zl = [=](int b, int kp) -> ull { return ld8(h2 + b * 512 + 2 * kp); };
        auto st = [=](int b, int col, float v) { st4(S + S_IDX(rr, tt, ee, b) + col, v); };
        p4<1>(W2, 512, B2, sub * 64, 0, 512, 1, 0, 0, nullptr, nullptr,
              cT, 0, nullptr, 0, lds, &sflag, zl, st);
      }
    }
  }

  // ======== FF1: rows=64 (t,b), K=2048, 32 col-tiles per e ================
  for (int r = 0; r < 4; ++r) waitge(cptr(C_C + e * 4 + r), 128u);
  {
    const float* S = p.S; const int ee = e;
    auto zl = [=](int row, int kp) -> ull {
      int k = 2 * kp, tt = row >> 2, b = row & 3, seg = k >> 9;
      return ld8(S + S_IDX(seg, tt, ee, b) + (k & 511));
    };
    float* g = p.g + (size_t)e * 131072;
    auto st = [=](int row, int col, float v) { st4(g + (size_t)row * 2048 + col, v); };
    int slot = w >> 4;
    p64<1>(p.ffW0 + (size_t)e * 4194304, 2048, p.ffb0 + e * 2048, slot * 64, 0, 2048,
           0, 0, 0, nullptr, nullptr, cptr(C_FFG + e), 0, nullptr, 0,
           lds, &sflag, zl, st);
  }
  waitge(cptr(C_FFG + e), 32u);
  // ======== FF2: K=2048 split 4; completion broadcast to flagFF ===========
  {
    int ct = w >> 6, kc2 = (w >> 4) & 3;
    const float* g = p.g + (size_t)e * 131072;
    auto zl = [=](int row, int kp) -> ull { return ld8(g + (size_t)row * 2048 + 2 * kp); };
    float* eo = p.eo; const int ee = e;
    auto st = [=](int row, int col, float v) {
      int tt = row >> 2, b = row & 3;
      st4(eo + (size_t)((tt * 16 + ee) * 4 + b) * 512 + col, v);
    };
    p64<4>(p.ffW1 + (size_t)e * 1048576, 512, p.ffb1 + e * 512, ct * 64,
           kc2 * 512, (kc2 + 1) * 512, 2, kc2, 4u,
           cptr(C_KF2 + e * 8 + ct), p.pF2 + (size_t)(e * 8 + ct) * 16384,
           cptr(C_FFO), 128u, cptr(C_FFLAG), 1u, lds, &sflag, zl, st);
  }

  // ======== L0a: batched eo @ dW0[:8192] over all 64 (t,b) rows ===========
  // state-independent part of decoder layer 0, weights read ONCE (67 MB)
  wait_epoch(myline_ff, 1u);
  const int tile = w >> 4, kD = w & 15;   // 32 tiles x 16 kc
  const int tileO = w >> 5, kO = w & 31;  // out: 16 tiles x 32 kc
  {
    const float* eo = p.eo;
    auto zl = [=](int row, int kp) -> ull {
      int k = 2 * kp, tt = row >> 2, b = row & 3, e2 = k >> 9;
      return ld8(eo + (size_t)((tt * 16 + e2) * 4 + b) * 512 + (k & 511));
    };
    float* hp = p.hd_pre;
    auto st = [=](int row, int col, float v) { st4(hp + (size_t)row * 2048 + col, v); };
    p64<16>(p.dW0, 2048, p.db0, tile * 64, kD * 512, (kD + 1) * 512, 2, kD, 16u,
            cptr(C_KL0 + tile), p.pF2 + (size_t)tile * 65536,
            cptr(C_L0C), 32u, cptr(C_L0FLAG), 1u, lds, &sflag, zl, st);
  }
  wait_epoch(myline_l0, 1u);

  // ======== DECODER: sequential over t; serial K only 1024 ===============
  {
    const float* dW0b = p.dW0 + (size_t)8192 * 2048;  // state rows of dW0
    for (int t = 0; t < 16; ++t) {
      if (t) wait_epoch(myline_out, (unsigned)t);
      {  // L0b: state part K=1024 + hd_pre (eo part + bias) -> gelu
        const float* dob = p.dob; const int tt = t;
        auto zl = [=](int b, int kpg) -> ull {
          return tt ? ld8(dob + b * 1024 + 2 * kpg) : 0ull;
        };
        const float* hp = p.hd_pre; float* hd = p.hd0;
        auto st = [=](int b, int col, float v) {
          v += ld4(hp + (size_t)(tt * 4 + b) * 2048 + col);
          v = act_apply(0, v);
          st4(hd + b * 2048 + col, v);
        };
        p4<16>(dW0b, 2048, nullptr, tile * 64, kD * 64, 64, 2, kD, 80u * t + 16u,
               cptr(C_KD + tile), p.pD + (size_t)tile * 4096,
               cptr(C_DC + 0), 32u * (t + 1), cptr(C_DFLAG + 0 * 64), (unsigned)(t + 1),
               lds, &sflag, zl, st);
      }
      for (int l = 1; l <= 4; ++l) {
        wait_epoch(cptr(C_DFLAG + (l - 1) * 64 + (w & 63)), (unsigned)(t + 1));
        const float* hin = (l & 1) ? p.hd0 : p.hd1;
        float* hout = (l & 1) ? p.hd1 : p.hd0;
        auto zl = [=](int b, int kp) -> ull { return ld8(hin + b * 2048 + 2 * kp); };
        auto st = [=](int b, int col, float v) { st4(hout + b * 2048 + col, v); };
        p4<16>(p.dWh + (size_t)(l - 1) * 4194304, 2048, p.dbh + (size_t)(l - 1) * 2048,
               tile * 64, kD * 128, 128, 0, kD, 80u * t + 16u * (l + 1),
               cptr(C_KD + tile), p.pD + (size_t)tile * 4096,
               cptr(C_DC + l), 32u * (t + 1), cptr(C_DFLAG + l * 64), (unsigned)(t + 1),
               lds, &sflag, zl, st);
      }
      wait_epoch(cptr(C_DFLAG + 4 * 64 + (w & 63)), (unsigned)(t + 1));
      {  // out layer: tanh -> d_out and dec state
        const float* hin = p.hd0; float* dob = p.dob; float* outp = p.out; const int tt = t;
        auto zl = [=](int b, int kp) -> ull { return ld8(hin + b * 2048 + 2 * kp); };
        auto st = [=](int b, int col, float v) {
          outp[(size_t)(b * 16 + tt) * 1024 + col] = v;  // host-visible
          st4(dob + b * 1024 + col, v);
        };
        p4<32>(p.dWo, 1024, p.dbo, tileO * 64, kO * 64, 64, 1, kO, 32u * (t + 1),
               cptr(C_KDO + tileO), p.pD + (size_t)tileO * 8192,
               cptr(C_DC + 5), 16u * (t + 1), cptr(C_OFLAG), (unsigned)(t + 1),
               lds, &sflag, zl, st);
      }
    }
  }
}

extern "C" void kernel_launch(void* const* d_in, const int* in_sizes, int n_in,
                              void* d_out, int out_size, void* d_ws, size_t ws_size,
                              hipStream_t stream) {
  hipMemsetAsync(d_ws, 0, 65536, stream);  // zero padded counters + flags

  P p;
  p.x    = (const float*)d_in[0];
  p.e0W0 = (const float*)d_in[1];  p.e0b0 = (const float*)d_in[2];
  p.e0W1 = (const float*)d_in[3];  p.e0b1 = (const float*)d_in[4];
  p.e0W2 = (const float*)d_in[5];  p.e0b2 = (const float*)d_in[6];
  p.erW0 = (const float*)d_in[7];  p.erb0 = (const float*)d_in[8];
  p.erW1 = (const float*)d_in[9];  p.erb1 = (const float*)d_in[10];
  p.erW2 = (const float*)d_in[11]; p.erb2 = (const float*)d_in[12];
  p.ffW0 = (const float*)d_in[13]; p.ffb0 = (const float*)d_in[14];
  p.ffW1 = (const float*)d_in[15]; p.ffb1 = (const float*)d_in[16];
  p.dW0  = (const float*)d_in[17]; p.db0  = (const float*)d_in[18];
  p.dWh  = (const float*)d_in[19]; p.dbh  = (const float*)d_in[20];
  p.dWo  = (const float*)d_in[21]; p.dbo  = (const float*)d_in[22];

  float* base = (float*)((char*)d_ws + 65536);
  p.S      = base; base += 2097152;  // 4*16*16*4*512
  p.h1     = base; base += 131072;   // 16*4 cells * 4*512
  p.h2     = base; base += 131072;
  p.g      = base; base += 2097152;  // 16*64*2048
  p.eo     = base; base += 524288;   // 16*16*4*512
  p.hd_pre = base; base += 131072;   // 64*2048
  p.hd0    = base; base += 8192;
  p.hd1    = base; base += 8192;
  p.dob    = base; base += 4096;
  p.pF2    = base; base += 2097152;  // FF2 partials; reused by L0a (after FF done)
  p.pD     = base; base += 131072;   // 32*16*256 == 16*32*256

  p.cnt = (unsigned*)d_ws;
  p.out = (float*)d_out;

  hipLaunchKernelGGL(hrnn, dim3(512), dim3(256), 0, stream, p);
}